// Round 7
// baseline (88.454 us; speedup 1.0000x reference)
//
#include <hip/hip_runtime.h>
#include <hip/hip_bf16.h>

// SkeletalConv via MFMA: out[co,e,t] = sum_k (Wk x Xk)[co,t], 3 taps.
// x: (16, 25, 65536) f32, W: (48, 16, 16, 3) f32, b: (48, 16) f32
// out: (16, 24, 65534) f32
// out[co,e,t] = 0.5*sum_{j,ci,k} W[2e+j,co,ci,k]*x[ci,e+j,t+k] + 0.5*(b[2e,co]+b[2e+1,co])
//
// Per edge, K-dim kk=(ci,j) is 32 = one mfma_f32_16x16x32_bf16 per tap.
// A = bf16(0.5*W) per-lane prepacked (d_ws). B built in registers: one
// dwordx4 per (tc,row) covers all 3 taps (consecutive cols); packed with
// v_cvt_pk_bf16_f32. All loads of an iteration hoisted -> ~32 in flight.
// Tail t-range handled by a separate template instantiation (SH=1) that
// loads at col-1 and uses elements 1..3 (no dynamic indexing, no OOB).

#define NJ    25
#define LSEQ  65536
#define NE    24
#define LOUTN (LSEQ - 2)               // 65534 valid t
#define NWA   (NE * 3 * 64 * 4)        // 18432 packed dwords
#define NBR   (NE * 16)                // 384 folded biases

typedef __attribute__((ext_vector_type(8))) short bf16x8;
typedef __attribute__((ext_vector_type(4))) float f32x4;

static __device__ __forceinline__ unsigned short f2bf(float f) {
    unsigned u = __float_as_uint(f);
    u += 0x7FFFu + ((u >> 16) & 1u);   // RNE
    return (unsigned short)(u >> 16);
}

static __device__ __forceinline__ unsigned cvtpk(float lo, float hi) {
    union { __hip_bfloat162 h; unsigned u; } cv;
    cv.h = __float22bfloat162_rn(make_float2(lo, hi));   // v_cvt_pk_bf16_f32
    return cv.u;
}

// Wa[((e*3+k)*64+l)*4+d] = pack(bf16(0.5*W[2e+j,co,ci,k]) for i=2d,2d+1)
//   with co=l&15, g=l>>4, kk=8g+i, ci=kk>>1, j=kk&1.
// Br[e*16+co] = 0.5*(b[2e,co]+b[2e+1,co])
__global__ void repack_kernel(const float* __restrict__ W, const float* __restrict__ b,
                              unsigned* __restrict__ Wa, float* __restrict__ Br)
{
    int idx = blockIdx.x * 256 + threadIdx.x;
    if (idx < NWA) {
        int d = idx & 3;
        int l = (idx >> 2) & 63;
        int k = (idx >> 8) % 3;
        int e = (idx >> 8) / 3;
        int g = l >> 4, co = l & 15;
        unsigned packed = 0;
        #pragma unroll
        for (int h = 0; h < 2; ++h) {
            int i  = 2 * d + h;
            int kk = 8 * g + i;
            int ci = kk >> 1, j = kk & 1;
            float w = 0.5f * W[(((2 * e + j) * 16 + co) * 16 + ci) * 3 + k];
            packed |= (unsigned)f2bf(w) << (16 * h);
        }
        Wa[idx] = packed;
    }
    if (idx < NBR) {
        int e = idx >> 4, co = idx & 15;
        Br[idx] = 0.5f * (b[(2 * e) * 16 + co] + b[(2 * e + 1) * 16 + co]);
    }
}

// SH=0: float4 at col, taps use elements 0..2 (main range, always in-bounds).
// SH=1: float4 at min(col,65533)-1, taps use elements 1..3 (tail range).
template<int SH>
__global__ __launch_bounds__(256)
void skel_mfma_kernel(const float* __restrict__ x,
                      const unsigned* __restrict__ Wa,
                      const float* __restrict__ Br,
                      float* __restrict__ out, int bxoff)
{
    const int e  = blockIdx.y;
    const int bx = blockIdx.x + bxoff;
    const int wv = threadIdx.x >> 6;
    const int l  = threadIdx.x & 63;
    const int g  = l >> 4, lc = l & 15;

    // ---- A fragments (3 taps), per-lane prepacked ----
    union { uint4 q; bf16x8 v; } A[3];
    #pragma unroll
    for (int k = 0; k < 3; ++k)
        A[k].q = *reinterpret_cast<const uint4*>(Wa + ((e * 3 + k) * 64 + l) * 4);

    const float4 bias = *reinterpret_cast<const float4*>(Br + e * 16 + g * 4);

    // uniform row bases (SGPR); row for (g,i): ci=4g+(i>>1), joint=e+(i&1)
    const float* xb[8];
    #pragma unroll
    for (int i = 0; i < 8; ++i)
        xb[i] = x + (size_t)((i >> 1) * NJ + e + (i & 1)) * LSEQ;
    const int gofs = g * (4 * NJ * LSEQ);          // per-lane row-group offset (elems)

    const int t0w = (bx * 4 + wv) * 256;

    #pragma unroll 1
    for (int it = 0; it < 4; ++it) {
        const int tb = t0w + it * 64;

        // ---- hoisted loads: 32 x dwordx4, ~all in flight ----
        int ofs[4];
        #pragma unroll
        for (int tc = 0; tc < 4; ++tc) {
            int col = tb + tc * 16 + lc;
            int be  = SH ? (min(col, LSEQ - 3) - 1) : col;
            ofs[tc] = gofs + be;
        }
        f32x4 P[4][8];
        #pragma unroll
        for (int tc = 0; tc < 4; ++tc)
            #pragma unroll
            for (int i = 0; i < 8; ++i)
                P[tc][i] = *reinterpret_cast<const f32x4*>(xb[i] + ofs[tc]);

        // ---- pack + MFMA ----
        f32x4 C[4];
        #pragma unroll
        for (int tc = 0; tc < 4; ++tc) {
            C[tc][0] = bias.x; C[tc][1] = bias.y;
            C[tc][2] = bias.z; C[tc][3] = bias.w;
        }
        #pragma unroll
        for (int tc = 0; tc < 4; ++tc) {
            #pragma unroll
            for (int k = 0; k < 3; ++k) {
                union { unsigned u[4]; bf16x8 v8; } B;
                #pragma unroll
                for (int d = 0; d < 4; ++d)
                    B.u[d] = cvtpk(P[tc][2 * d][SH + k], P[tc][2 * d + 1][SH + k]);
                C[tc] = __builtin_amdgcn_mfma_f32_16x16x32_bf16(A[k].v, B.v8, C[tc], 0, 0, 0);
            }
        }

        // ---- store: C row = co = g*4+r, col t = tb+tc*16+lc ----
        #pragma unroll
        for (int tc = 0; tc < 4; ++tc) {
            const int t = tb + tc * 16 + lc;
            if (t < LOUTN) {
                #pragma unroll
                for (int r = 0; r < 4; ++r)
                    out[(size_t)((g * 4 + r) * NE + e) * LOUTN + t] = C[tc][r];
            }
        }
    }
}

extern "C" void kernel_launch(void* const* d_in, const int* in_sizes, int n_in,
                              void* d_out, int out_size, void* d_ws, size_t ws_size,
                              hipStream_t stream)
{
    const float* x = (const float*)d_in[0];
    const float* W = (const float*)d_in[1];
    const float* b = (const float*)d_in[2];
    float* out     = (float*)d_out;

    unsigned* Wa = (unsigned*)d_ws;          // 18432 dwords
    float*    Br = (float*)(Wa + NWA);       // 384 floats

    repack_kernel<<<(NWA + 255) / 256, 256, 0, stream>>>(W, b, Wa, Br);

    dim3 gmain(63, NE);                      // cols 0 .. 64511 (never OOB)
    skel_mfma_kernel<0><<<gmain, 256, 0, stream>>>(x, Wa, Br, out, 0);
    dim3 gtail(1, NE);                       // cols 64512 .. 65535 (shifted loads)
    skel_mfma_kernel<1><<<gtail, 256, 0, stream>>>(x, Wa, Br, out, 63);
}

// Round 8
// 46.223 us; speedup vs baseline: 1.9136x; 1.9136x over previous
//
#include <hip/hip_runtime.h>
#include <hip/hip_bf16.h>

// SkeletalConv via MFMA + LDS staging.
// x: (16, 25, 65536) f32, W: (48, 16, 16, 3) f32, b: (48, 16) f32
// out: (16, 24, 65534) f32
// out[co,e,t] = 0.5*sum_{j,ci,k} W[2e+j,co,ci,k]*x[ci,e+j,t+k] + 0.5*(b[2e,co]+b[2e+1,co])
//
// Per edge, K-dim kk=(ci,j) is 32 = one mfma_f32_16x16x32_bf16 per tap.
// Block = (edge, 256-col chunk). Stage: coalesced float4 loads of x rows
// (ci, e) and (ci, e+1), cvt_pk to bf16 pairs, ds_write_b128 ->
// lds[ci][col] = dword(bf16 x[ci,e,col] | bf16 x[ci,e+1,col]<<16), which IS
// B-fragment slot d's dword (kk=(ci,j) enumeration matches Wa). Compute:
// 4 ds_read_b32 per fragment, 3 taps reuse the tile. Tail fused (halo
// clamped, stores guarded).

#define NJ    25
#define LSEQ  65536
#define NE    24
#define LOUTN (LSEQ - 2)               // 65534 valid t
#define NWA   (NE * 3 * 64 * 4)        // 18432 packed dwords
#define NBR   (NE * 16)                // 384 folded biases
#define CW    260                      // LDS row width in dwords (1040B, 16B-mult)

typedef __attribute__((ext_vector_type(8))) short bf16x8;
typedef __attribute__((ext_vector_type(4))) float f32x4;

static __device__ __forceinline__ unsigned short f2bf(float f) {
    unsigned u = __float_as_uint(f);
    u += 0x7FFFu + ((u >> 16) & 1u);   // RNE
    return (unsigned short)(u >> 16);
}

static __device__ __forceinline__ unsigned cvtpk(float lo, float hi) {
    union { __hip_bfloat162 h; unsigned u; } cv;
    cv.h = __float22bfloat162_rn(make_float2(lo, hi));   // v_cvt_pk_bf16_f32
    return cv.u;
}

// Wa[((e*3+k)*64+l)*4+d] = pack(bf16(0.5*W[2e+j,co,ci,k]) for i=2d,2d+1)
//   with co=l&15, g=l>>4, kk=8g+i, ci=kk>>1, j=kk&1.
// Br[e*16+co] = 0.5*(b[2e,co]+b[2e+1,co])
__global__ void repack_kernel(const float* __restrict__ W, const float* __restrict__ b,
                              unsigned* __restrict__ Wa, float* __restrict__ Br)
{
    int idx = blockIdx.x * 256 + threadIdx.x;
    if (idx < NWA) {
        int d = idx & 3;
        int l = (idx >> 2) & 63;
        int k = (idx >> 8) % 3;
        int e = (idx >> 8) / 3;
        int g = l >> 4, co = l & 15;
        unsigned packed = 0;
        #pragma unroll
        for (int h = 0; h < 2; ++h) {
            int i  = 2 * d + h;
            int kk = 8 * g + i;
            int ci = kk >> 1, j = kk & 1;
            float w = 0.5f * W[(((2 * e + j) * 16 + co) * 16 + ci) * 3 + k];
            packed |= (unsigned)f2bf(w) << (16 * h);
        }
        Wa[idx] = packed;
    }
    if (idx < NBR) {
        int e = idx >> 4, co = idx & 15;
        Br[idx] = 0.5f * (b[(2 * e) * 16 + co] + b[(2 * e + 1) * 16 + co]);
    }
}

__global__ __launch_bounds__(256)
void skel_mfma_kernel(const float* __restrict__ x,
                      const unsigned* __restrict__ Wa,
                      const float* __restrict__ Br,
                      float* __restrict__ out)
{
    __shared__ unsigned lds[16 * CW];   // [ci][col] bf16 pair (joint e | e+1)

    const int e   = blockIdx.y;
    const int tb  = blockIdx.x * 256;
    const int tid = threadIdx.x;
    const int l   = tid & 63, wv = tid >> 6;
    const int g   = l >> 4,  lc = l & 15;

    // ---- stage: 16 ci-rows x 256 cols (+2 halo) ----
    {
        const int rp = tid >> 4;                    // ci
        const int q0 = tid & 15;
        const float* xlo = x + (size_t)(rp * NJ + e) * LSEQ + tb;
        #pragma unroll
        for (int s = 0; s < 4; ++s) {
            const int c = 4 * q0 + 64 * s;          // 16B-aligned, never OOB (tb+255<=65535)
            float4 lo = *reinterpret_cast<const float4*>(xlo + c);
            float4 hi = *reinterpret_cast<const float4*>(xlo + LSEQ + c);
            uint4 pk;
            pk.x = cvtpk(lo.x, hi.x);
            pk.y = cvtpk(lo.y, hi.y);
            pk.z = cvtpk(lo.z, hi.z);
            pk.w = cvtpk(lo.w, hi.w);
            *reinterpret_cast<uint4*>(&lds[rp * CW + c]) = pk;
        }
    }
    if (tid < 32) {                                 // halo cols 256,257
        const int rp = tid >> 1, h = tid & 1;
        const int gc = min(tb + 256 + h, LSEQ - 1); // clamp (last chunk only)
        const float* xl = x + (size_t)(rp * NJ + e) * LSEQ;
        lds[rp * CW + 256 + h] = cvtpk(xl[gc], xl[gc + LSEQ]);
    }
    __syncthreads();

    // ---- compute: wave wv owns cols wv*64 .. wv*64+63 ----
    union { uint4 q; bf16x8 v; } A[3];
    #pragma unroll
    for (int k = 0; k < 3; ++k)
        A[k].q = *reinterpret_cast<const uint4*>(Wa + ((e * 3 + k) * 64 + l) * 4);

    const float4 bias = *reinterpret_cast<const float4*>(Br + e * 16 + g * 4);

    #pragma unroll
    for (int tc = 0; tc < 4; ++tc) {
        const int cb = wv * 64 + tc * 16 + lc;      // col within chunk
        f32x4 C;
        C[0] = bias.x; C[1] = bias.y; C[2] = bias.z; C[3] = bias.w;
        #pragma unroll
        for (int k = 0; k < 3; ++k) {
            union { unsigned u[4]; bf16x8 v8; } B;
            #pragma unroll
            for (int d = 0; d < 4; ++d)
                B.u[d] = lds[(4 * g + d) * CW + cb + k];
            C = __builtin_amdgcn_mfma_f32_16x16x32_bf16(A[k].v, B.v8, C, 0, 0, 0);
        }
        const int t = tb + cb;
        if (t < LOUTN) {
            #pragma unroll
            for (int r = 0; r < 4; ++r)
                out[(size_t)((g * 4 + r) * NE + e) * LOUTN + t] = C[r];
        }
    }
}

extern "C" void kernel_launch(void* const* d_in, const int* in_sizes, int n_in,
                              void* d_out, int out_size, void* d_ws, size_t ws_size,
                              hipStream_t stream)
{
    const float* x = (const float*)d_in[0];
    const float* W = (const float*)d_in[1];
    const float* b = (const float*)d_in[2];
    float* out     = (float*)d_out;

    unsigned* Wa = (unsigned*)d_ws;          // 18432 dwords
    float*    Br = (float*)(Wa + NWA);       // 384 floats

    repack_kernel<<<(NWA + 255) / 256, 256, 0, stream>>>(W, b, Wa, Br);

    dim3 grid((LOUTN + 255) / 256, NE);      // 256 x 24 blocks
    skel_mfma_kernel<<<grid, 256, 0, stream>>>(x, Wa, Br, out);
}